// Round 6
// baseline (101.435 us; speedup 1.0000x reference)
//
#include <hip/hip_runtime.h>

// QuantumAttention: B=8, S=2048, E=8, H=2, D=4, NQ=8
//
// Accounting across R5..R10: total = fill ~41 + attn + merge + ~18us fixed
// (graph/harness) overhead. attn9 (M=2, LDS broadcast) = 26us; merge ~2us.
// attn9 is LDS-pipe bound: 2 broadcast ds_read_b128 per (wave,j) x ~12cyc
// = 20.5us/CU vs ~11us VALU. R10 (M=4 under 64-VGPR cap) spilled: +9us.
// R11: broadcast moved to the VALU pipe via DPP wavefront rotate
// (v_mov_b32_dpp WAVE_ROL1). Each lane stages K/V for its OWN j in regs
// (R7-validated math, identical bits); 64-step ping-pong rotation sweeps
// all j through every lane. Main loop: zero LDS, zero barriers.
// Rotation adds 8 movs/step (~3.4us/SIMD); predict attn ~15-17us.
// NOTE vs R7: readlane failed on VALU->SGPR->VALU hazard; DPP is
// VALU->VALU forwarding, no such stall.
//
// Quantum circuit closed-form: c_w = cos(tok[w]+tok[w%4]);
// z[0]=c1..c7, z[q>=1]=c0..cq. Softmax one-pass (scores bounded, fp32 safe);
// 0.5*log2(e) folded into Wq so inner exp is bare v_exp_f32 (exp2).

#define SS 2048
#define EE 8

__device__ __forceinline__ float rot1(float v) {
    // full-wave rotate: lane l receives lane (l-1)&63's value (WAVE_ROL1=0x134)
    return __uint_as_float(__builtin_amdgcn_mov_dpp(
        __float_as_uint(v), 0x134, 0xF, 0xF, true));
}

// grid 2048: bid = b<<8 | h<<7 | rt<<3 | jw.  256 threads = 4 waves.
// Block: rows rt*128..+127 (2 per lane), j-window jw*256..+255; wave w owns
// j = jw*256 + w*64 + lane (K/V in that lane's registers, swept by DPP).
extern "C" __global__ __launch_bounds__(256, 8)
void qa_attn11(const float* __restrict__ x, const float* __restrict__ Wq,
               const float* __restrict__ Wk, const float* __restrict__ Wv,
               float* __restrict__ wsD, float4* __restrict__ wsA) {
    __shared__ float wrow[96];                    // wq'(scaled), wk, wv
    __shared__ float rden[3 * 128];               // waves 1..3 partials
    __shared__ __align__(16) float4 racc[3 * 128];// 6 KB

    const int bid = blockIdx.x;
    const int jw = bid & 7, rt = (bid >> 3) & 15, h = (bid >> 7) & 1, b = bid >> 8;
    const int tid = threadIdx.x, lane = tid & 63, w = tid >> 6;

    if (tid < 96) {
        const int grp = tid >> 5, d = (tid >> 3) & 3, e = tid & 7;
        const float* W = (grp == 0) ? Wq : (grp == 1 ? Wk : Wv);
        float val = W[(h * 4 + d) * EE + e];
        if (grp == 0) val *= 0.72134752044f;   // 0.5 * log2(e)
        wrow[tid] = val;
    }
    __syncthreads();   // wrow ready

    // ---- this lane's own j: K,V staged into registers (ping-pong set A) ----
    float ka[4], va[4], kb[4], vb[4];
    {
        const int j = jw * 256 + tid;   // w*64 + lane folded in via tid
        const float* xp = x + ((size_t)(b * SS + j)) * EE;
        float xv[8];
        *(float4*)&xv[0] = *(const float4*)xp;
        *(float4*)&xv[4] = *(const float4*)(xp + 4);
        #pragma unroll
        for (int d = 0; d < 4; ++d) {
            float sk = 0.f, sv = 0.f;
            #pragma unroll
            for (int e = 0; e < 8; ++e) {
                sk += xv[e] * wrow[32 + d * 8 + e];
                sv += xv[e] * wrow[64 + d * 8 + e];
            }
            ka[d] = sk; va[d] = sv;
        }
    }

    // ---- q' (log2-scaled) for this lane's 2 rows ----
    float q[2][4];
    const int row0 = rt * 128 + lane;
    #pragma unroll
    for (int m = 0; m < 2; ++m) {
        const float* xp = x + ((size_t)(b * SS + row0 + m * 64)) * EE;
        float xv[8];
        *(float4*)&xv[0] = *(const float4*)xp;
        *(float4*)&xv[4] = *(const float4*)(xp + 4);
        #pragma unroll
        for (int d = 0; d < 4; ++d) {
            float s = 0.f;
            #pragma unroll
            for (int e = 0; e < 8; ++e) s += xv[e] * wrow[d * 8 + e];
            q[m][d] = s;
        }
    }
    // no barrier: main loop uses only this wave's registers

    // ---- 64 j swept through every lane by DPP rotation, 2 rows per lane ----
    float den[2] = {};
    float acc[2][4] = {};
    #pragma unroll 4
    for (int t = 0; t < 32; ++t) {
        // rotate A->B (next j), then consume A; compiler interleaves
        #pragma unroll
        for (int c = 0; c < 4; ++c) { kb[c] = rot1(ka[c]); vb[c] = rot1(va[c]); }
        #pragma unroll
        for (int m = 0; m < 2; ++m) {
            const float s = q[m][0] * ka[0] + q[m][1] * ka[1]
                          + q[m][2] * ka[2] + q[m][3] * ka[3];
            const float e = __builtin_amdgcn_exp2f(s);
            den[m] += e;
            acc[m][0] += e * va[0]; acc[m][1] += e * va[1];
            acc[m][2] += e * va[2]; acc[m][3] += e * va[3];
        }
        // rotate B->A, consume B
        #pragma unroll
        for (int c = 0; c < 4; ++c) { ka[c] = rot1(kb[c]); va[c] = rot1(vb[c]); }
        #pragma unroll
        for (int m = 0; m < 2; ++m) {
            const float s = q[m][0] * kb[0] + q[m][1] * kb[1]
                          + q[m][2] * kb[2] + q[m][3] * kb[3];
            const float e = __builtin_amdgcn_exp2f(s);
            den[m] += e;
            acc[m][0] += e * vb[0]; acc[m][1] += e * vb[1];
            acc[m][2] += e * vb[2]; acc[m][3] += e * vb[3];
        }
    }

    // ---- single-stage reduce: waves 1..3 park, wave 0 merges + writes ----
    if (w > 0) {
        #pragma unroll
        for (int m = 0; m < 2; ++m) {
            rden[(w - 1) * 128 + lane + m * 64] = den[m];
            racc[(w - 1) * 128 + lane + m * 64] =
                make_float4(acc[m][0], acc[m][1], acc[m][2], acc[m][3]);
        }
    }
    __syncthreads();
    if (w == 0) {
        #pragma unroll
        for (int m = 0; m < 2; ++m) {
            const int r = lane + m * 64;
            float d = den[m] + rden[r] + rden[128 + r] + rden[256 + r];
            float4 a1 = racc[r], a2 = racc[128 + r], a3 = racc[256 + r];
            float4 a = make_float4(acc[m][0] + a1.x + a2.x + a3.x,
                                   acc[m][1] + a1.y + a2.y + a3.y,
                                   acc[m][2] + a1.z + a2.z + a3.z,
                                   acc[m][3] + a1.w + a2.w + a3.w);
            const size_t idx = ((size_t)((b * 2 + h) * 8 + jw)) * SS + row0 + m * 64;
            wsD[idx] = d;
            wsA[idx] = a;
        }
    }
}

// ---- merge + quantum: 2 threads/token (one per head), shfl_xor exchange.
// UNCHANGED from R9 (bit-identical).
extern "C" __global__ __launch_bounds__(256)
void qa_merge11(const float* __restrict__ wsD, const float4* __restrict__ wsA,
                const float* __restrict__ Wo, float* __restrict__ out) {
    __shared__ float wo[64];
    const int tid = threadIdx.x;
    if (tid < 64) wo[tid] = Wo[tid];
    __syncthreads();

    const int gt = blockIdx.x * 256 + tid;   // 0..32767
    const int g = gt >> 1, h = gt & 1;       // token, head
    const int b = g >> 11, s = g & 2047;

    float den = 0.f, a0 = 0.f, a1 = 0.f, a2 = 0.f, a3 = 0.f;
    #pragma unroll
    for (int sl = 0; sl < 8; ++sl) {
        const size_t idx = ((size_t)((b * 2 + h) * 8 + sl)) * SS + s;
        den += wsD[idx];
        const float4 p = wsA[idx];
        a0 += p.x; a1 += p.y; a2 += p.z; a3 += p.w;
    }
    const float inv = 1.f / den;
    float own[4] = {a0 * inv, a1 * inv, a2 * inv, a3 * inv};
    float oth[4];
    #pragma unroll
    for (int c = 0; c < 4; ++c) oth[c] = __shfl_xor(own[c], 1);

    float tok[8];
    #pragma unroll
    for (int c = 0; c < 4; ++c) {
        tok[c]     = h ? oth[c] : own[c];
        tok[4 + c] = h ? own[c] : oth[c];
    }

    float cc[8];
    #pragma unroll
    for (int ww = 0; ww < 8; ++ww) cc[ww] = __cosf(tok[ww] + tok[ww & 3]);

    float z[8];
    float p = 1.f;
    #pragma unroll
    for (int qq = 1; qq < 8; ++qq) { p *= cc[qq]; z[qq] = p; }
    z[0] = p;                       // c1..c7
    #pragma unroll
    for (int qq = 1; qq < 8; ++qq) z[qq] *= cc[0];   // c0..cq

    // this thread writes outputs f = h*4 .. h*4+3
    float y[4];
    #pragma unroll
    for (int f = 0; f < 4; ++f) {
        float sum = 0.f;
        #pragma unroll
        for (int qq = 0; qq < 8; ++qq) sum += z[qq] * wo[(h * 4 + f) * 8 + qq];
        y[f] = sum;
    }
    float4* op = (float4*)(out + (size_t)g * 8) + h;
    *op = make_float4(y[0], y[1], y[2], y[3]);
}

extern "C" void kernel_launch(void* const* d_in, const int* in_sizes, int n_in,
                              void* d_out, int out_size, void* d_ws, size_t ws_size,
                              hipStream_t stream) {
    const float* x  = (const float*)d_in[0];
    const float* Wq = (const float*)d_in[1];
    const float* Wk = (const float*)d_in[2];
    const float* Wv = (const float*)d_in[3];
    const float* Wo = (const float*)d_in[4];
    float* out = (float*)d_out;

    float*  wsD = (float*)d_ws;                          // 16*8*2048 floats = 1 MB
    float4* wsA = (float4*)((char*)d_ws + (16 * 8 * 2048) * sizeof(float)); // 4 MB

    qa_attn11<<<dim3(2048), dim3(256), 0, stream>>>(x, Wq, Wk, Wv, wsD, wsA);
    qa_merge11<<<dim3(128), dim3(256), 0, stream>>>(wsD, wsA, Wo, out);
}